// Round 6
// baseline (1262.918 us; speedup 1.0000x reference)
//
#include <hip/hip_runtime.h>
#include <hip/hip_bf16.h>

typedef short bf16x8 __attribute__((ext_vector_type(8)));
typedef float f32x4  __attribute__((ext_vector_type(4)));
typedef unsigned short u16;
typedef unsigned int u32;

// ---- LDS: 4 waves x 6KB private transpose scratch, nothing else ----
#define LDS_BYTES 24576u    // + wid*6144 : q/P'/ctx'(2KB) | k(2KB) | v'(2KB)

// ---- workspace ----
#define WS_QKVW 0u          // 8 heads x 48 frags x 1KB  (frag = (ct*8+ks)*1024 + lane*16)
#define WS_OUTW 393216u     // 128 frags x 1KB           (frag = (ft*8+ks)*1024 + lane*16)
#define WS_QB   524288u     // [8][96] f32

// mask rows (bits 0..25); rows 26..31 dummy bit0 keeps pad rows finite
__constant__ u32 MASK32[32] = {
  0x0210000Fu,0x0210000Fu,0x0210000Fu,0x0210000Fu,
  0x026000F0u,0x026000F0u,0x026000F0u,0x026000F0u,
  0x03800F00u,0x03800F00u,0x03800F00u,0x03800F00u,
  0x0200F000u,0x0200F000u,0x0200F000u,0x0200F000u,
  0x020F0000u,0x020F0000u,0x020F0000u,0x020F0000u,
  0x0210000Fu,
  0x026000F0u,0x026000F0u,
  0x03800F00u,0x03800F00u,
  0x03FFFFFFu,
  0x1u,0x1u,0x1u,0x1u,0x1u,0x1u
};

__device__ __forceinline__ u16 f2bf(float f) {
  u32 u = __float_as_uint(f);
  u = (u + 0x7FFFu + ((u >> 16) & 1u)) >> 16;
  return (u16)u;
}
__device__ __forceinline__ u32 pk2(float a, float b) {
  return (u32)f2bf(a) | ((u32)f2bf(b) << 16);
}
__device__ __forceinline__ uint2 pk4(float a, float b, float c, float d) {
  uint2 r; r.x = pk2(a, b); r.y = pk2(c, d); return r;
}
// bijective 64B-row swizzle: XOR on the FULL byte offset (round-3-verified)
__device__ __forceinline__ u32 sw64(int row, int col2) {
  return (u32)((row * 64 + col2) ^ ((row & 7) << 4));
}

// ---- prep: fragment-order bf16 weight images + packed bias ----
__global__ __launch_bounds__(256)
void prep(const float* __restrict__ qkv_w, const float* __restrict__ qkv_b,
          const float* __restrict__ out_w, unsigned char* __restrict__ ws)
{
  int t = blockIdx.x * 256 + threadIdx.x;
  if (t < 24576) {                       // qkv frags: 8h x 48fr x 64 lanes
    int h = t / 3072, rem = t - h * 3072;
    int fr = rem >> 6, ln = rem & 63;
    int ct = fr >> 3, ks = fr & 7;
    int lr = ln & 15, lg = ln >> 4;
    int fg = (ct >> 1) * 256 + h * 32 + (ct & 1) * 16 + lr;
    const float* s = qkv_w + fg * 256 + ks * 32 + lg * 8;
    float4 v0 = *(const float4*)s, v1 = *(const float4*)(s + 4);
    uint4 o;
    o.x = pk2(v0.x, v0.y); o.y = pk2(v0.z, v0.w);
    o.z = pk2(v1.x, v1.y); o.w = pk2(v1.z, v1.w);
    *(uint4*)(ws + WS_QKVW + (u32)h * 49152u + (u32)fr * 1024u + (u32)ln * 16u) = o;
  } else if (t < 32768) {                // outw frags: 128fr x 64 lanes
    int g = t - 24576;
    int fr = g >> 6, ln = g & 63;
    int ft = fr >> 3, ks = fr & 7;
    int lr = ln & 15, lg = ln >> 4;
    const float* s = out_w + (ft * 16 + lr) * 256 + ks * 32 + lg * 8;
    float4 v0 = *(const float4*)s, v1 = *(const float4*)(s + 4);
    uint4 o;
    o.x = pk2(v0.x, v0.y); o.y = pk2(v0.z, v0.w);
    o.z = pk2(v1.x, v1.y); o.w = pk2(v1.z, v1.w);
    *(uint4*)(ws + WS_OUTW + (u32)fr * 1024u + (u32)ln * 16u) = o;
  } else if (t < 33536) {                // qkv bias [8][96]
    int i = t - 32768;
    int h = i / 96, j = i - h * 96;
    int ct = j >> 4, lr = j & 15;
    ((float*)(ws + WS_QB))[i] = qkv_b[(ct >> 1) * 256 + h * 32 + (ct & 1) * 16 + lr];
  }
}

__global__ __launch_bounds__(256, 4)
void brain_fused(const float* __restrict__ x,
                 const unsigned char* __restrict__ ws,
                 const float* __restrict__ out_b,
                 float* __restrict__ out)
{
  __shared__ char smem[LDS_BYTES] __attribute__((aligned(16)));
  const int tid  = threadIdx.x;
  const int lane = tid & 63;
  const int wid  = tid >> 6;          // 0..3 = batch within block
  const int lr   = lane & 15;
  const int lg   = lane >> 4;
  const size_t rb = (size_t)blockIdx.x * 104 + (size_t)wid * 26;
  const f32x4 zero = {0.f, 0.f, 0.f, 0.f};
  const u32 sb = (u32)wid * 6144u;    // q/P'/ctx' @ sb, k @ +2048, v' @ +4096

  // ---- x A-fragments into registers (reused for all 8 heads) ----
  bf16x8 af[2][8];
#pragma unroll
  for (int st = 0; st < 2; ++st) {
    int s = st * 16 + lr;
    const float* xp = x + (rb + (size_t)(s < 26 ? s : 0)) * 256;
#pragma unroll
    for (int ks = 0; ks < 8; ++ks) {
      const float* p = xp + ks * 32 + lg * 8;
      float4 v0 = *(const float4*)p, v1 = *(const float4*)(p + 4);
      union { u32 u[4]; bf16x8 v; } tt;
      tt.u[0] = pk2(v0.x, v0.y); tt.u[1] = pk2(v0.z, v0.w);
      tt.u[2] = pk2(v1.x, v1.y); tt.u[3] = pk2(v1.z, v1.w);
      af[st][ks] = tt.v;
    }
  }

  const u32 mq0 = MASK32[lr];
  const u32 mq1 = MASK32[16 + lr];
  const float* qb = (const float*)(ws + WS_QB);

  bf16x8 cf[8][2];                     // ctx frags (A-operand of out-proj)

#pragma unroll
  for (int h = 0; h < 8; ++h) {
    const unsigned char* wh = ws + WS_QKVW + (u32)h * 49152u;

    // ---- QKV GEMM: 32 rows x 96 feats, K=256; bias in acc init ----
    f32x4 acc[2][6];
#pragma unroll
    for (int ct = 0; ct < 6; ++ct) {
      float bb = qb[h * 96 + ct * 16 + lr];
      f32x4 bv = {bb, bb, bb, bb};
      acc[0][ct] = bv; acc[1][ct] = bv;
    }
#pragma unroll
    for (int ks = 0; ks < 8; ++ks) {
      bf16x8 bw[6];
#pragma unroll
      for (int ct = 0; ct < 6; ++ct)
        bw[ct] = *(const bf16x8*)(wh + (u32)((ct * 8 + ks) * 1024) + (u32)lane * 16u);
#pragma unroll
      for (int st = 0; st < 2; ++st)
#pragma unroll
        for (int ct = 0; ct < 6; ++ct)
          acc[st][ct] = __builtin_amdgcn_mfma_f32_16x16x32_bf16(af[st][ks], bw[ct], acc[st][ct], 0, 0, 0);
    }

    // ---- scratch: q[s][d], k[s][d] scalar; v'[d][s] packed b64 ----
#pragma unroll
    for (int st = 0; st < 2; ++st)
#pragma unroll
      for (int ct = 0; ct < 4; ++ct)
#pragma unroll
        for (int r = 0; r < 4; ++r) {
          int s = st * 16 + lg * 4 + r;
          if (s < 26) {
            int d = (ct & 1) * 16 + lr;
            u32 a = sb + (ct < 2 ? 0u : 2048u) + sw64(s, d * 2);
            *(u16*)(smem + a) = f2bf(acc[st][ct][r]);
          }
        }
#pragma unroll
    for (int st = 0; st < 2; ++st)
#pragma unroll
      for (int ct = 4; ct < 6; ++ct) {
        int d = (ct & 1) * 16 + lr;
        u32 a = sb + 4096u + sw64(d, (st * 16 + lg * 4) * 2);
        *(uint2*)(smem + a) = pk4(acc[st][ct][0], acc[st][ct][1], acc[st][ct][2], acc[st][ct][3]);
      }

    // ---- frag reads ----
    bf16x8 qf[2], kf[2], vf[2];
#pragma unroll
    for (int t = 0; t < 2; ++t) {
      u32 ro = sw64(t * 16 + lr, lg * 16);
      qf[t] = *(const bf16x8*)(smem + sb + ro);
      kf[t] = *(const bf16x8*)(smem + sb + 2048u + ro);
      vf[t] = *(const bf16x8*)(smem + sb + 4096u + ro);
    }

    // ---- scores^T = K * Q^T ----
    f32x4 sc[2][2];  // [s_k half][q half]
#pragma unroll
    for (int st = 0; st < 2; ++st)
#pragma unroll
      for (int qt = 0; qt < 2; ++qt)
        sc[st][qt] = __builtin_amdgcn_mfma_f32_16x16x32_bf16(kf[st], qf[qt], zero, 0, 0, 0);

    // ---- masked softmax over s_k (per q column); P'[q][s] packed b64 ----
#pragma unroll
    for (int qt = 0; qt < 2; ++qt) {
      u32 mrow = qt ? mq1 : mq0;
      float mx = -3.0e38f;
#pragma unroll
      for (int st = 0; st < 2; ++st)
#pragma unroll
        for (int r = 0; r < 4; ++r) {
          int sk = st * 16 + lg * 4 + r;
          if ((mrow >> sk) & 1u) mx = fmaxf(mx, sc[st][qt][r]);
        }
      mx = fmaxf(mx, __shfl_xor(mx, 16));
      mx = fmaxf(mx, __shfl_xor(mx, 32));
      float pex[2][4];
      float sum = 0.f;
#pragma unroll
      for (int st = 0; st < 2; ++st)
#pragma unroll
        for (int r = 0; r < 4; ++r) {
          int sk = st * 16 + lg * 4 + r;
          // exp(s/sqrt(32)) = exp2(s * log2(e)/sqrt(32))
          float p = ((mrow >> sk) & 1u) ? exp2f((sc[st][qt][r] - mx) * 0.25503486f) : 0.f;
          pex[st][r] = p; sum += p;
        }
      sum += __shfl_xor(sum, 16);
      sum += __shfl_xor(sum, 32);
      float ri = __builtin_amdgcn_rcpf(sum);
      int q = qt * 16 + lr;
#pragma unroll
      for (int st = 0; st < 2; ++st) {
        u32 a = sb + sw64(q, (st * 16 + lg * 4) * 2);
        *(uint2*)(smem + a) = pk4(pex[st][0] * ri, pex[st][1] * ri, pex[st][2] * ri, pex[st][3] * ri);
      }
    }

    // ---- ctx^T = V^T * P^T ----
    bf16x8 pf[2];
#pragma unroll
    for (int qt = 0; qt < 2; ++qt)
      pf[qt] = *(const bf16x8*)(smem + sb + sw64(qt * 16 + lr, lg * 16));
    f32x4 pv[2][2];  // [d half][q half]
#pragma unroll
    for (int dt = 0; dt < 2; ++dt)
#pragma unroll
      for (int qt = 0; qt < 2; ++qt)
        pv[dt][qt] = __builtin_amdgcn_mfma_f32_16x16x32_bf16(vf[dt], pf[qt], zero, 0, 0, 0);

    // ctx'[q][d] packed b64, then read ctx frags
#pragma unroll
    for (int dt = 0; dt < 2; ++dt)
#pragma unroll
      for (int qt = 0; qt < 2; ++qt) {
        int q = qt * 16 + lr;
        u32 a = sb + sw64(q, (dt * 16 + lg * 4) * 2);
        *(uint2*)(smem + a) = pk4(pv[dt][qt][0], pv[dt][qt][1], pv[dt][qt][2], pv[dt][qt][3]);
      }
#pragma unroll
    for (int qt = 0; qt < 2; ++qt)
      cf[h][qt] = *(const bf16x8*)(smem + sb + sw64(qt * 16 + lr, lg * 16));
  } // heads

  // ---- out-projection: out[q][f] = sum_h ctx_h @ outw_h^T + out_b ----
#pragma unroll
  for (int fc = 0; fc < 4; ++fc) {
    f32x4 oa[2][4];
#pragma unroll
    for (int j = 0; j < 4; ++j) {
      float bo = out_b[(fc * 4 + j) * 16 + lr];
      f32x4 bv = {bo, bo, bo, bo};
      oa[0][j] = bv; oa[1][j] = bv;
    }
#pragma unroll
    for (int ks = 0; ks < 8; ++ks) {
      bf16x8 bw[4];
#pragma unroll
      for (int j = 0; j < 4; ++j)
        bw[j] = *(const bf16x8*)(ws + WS_OUTW + (u32)(((fc * 4 + j) * 8 + ks) * 1024) + (u32)lane * 16u);
#pragma unroll
      for (int qt = 0; qt < 2; ++qt)
#pragma unroll
        for (int j = 0; j < 4; ++j)
          oa[qt][j] = __builtin_amdgcn_mfma_f32_16x16x32_bf16(cf[ks][qt], bw[j], oa[qt][j], 0, 0, 0);
    }
#pragma unroll
    for (int qt = 0; qt < 2; ++qt)
#pragma unroll
      for (int j = 0; j < 4; ++j)
#pragma unroll
        for (int r = 0; r < 4; ++r) {
          int qrow = qt * 16 + lg * 4 + r;
          if (qrow < 26)
            out[(rb + (size_t)qrow) * 256 + (fc * 4 + j) * 16 + lr] = oa[qt][j][r];
        }
  }
}

extern "C" void kernel_launch(void* const* d_in, const int* in_sizes, int n_in,
                              void* d_out, int out_size, void* d_ws, size_t ws_size,
                              hipStream_t stream) {
  (void)in_sizes; (void)n_in; (void)out_size; (void)ws_size;
  const float* x     = (const float*)d_in[0];
  const float* qkv_w = (const float*)d_in[1];
  const float* qkv_b = (const float*)d_in[2];
  const float* out_w = (const float*)d_in[3];
  const float* out_b = (const float*)d_in[4];
  unsigned char* ws = (unsigned char*)d_ws;
  float* out = (float*)d_out;

  prep<<<dim3(131), dim3(256), 0, stream>>>(qkv_w, qkv_b, out_w, ws);
  brain_fused<<<dim3(4096), dim3(256), 0, stream>>>(x, ws, out_b, out);
}

// Round 7
// 1127.655 us; speedup vs baseline: 1.1200x; 1.1200x over previous
//
#include <hip/hip_runtime.h>
#include <hip/hip_bf16.h>

typedef short bf16x8 __attribute__((ext_vector_type(8)));
typedef float f32x4  __attribute__((ext_vector_type(4)));
typedef unsigned short u16;
typedef unsigned int u32;

// ---- LDS: 4 waves x 6KB private transpose scratch, nothing else ----
#define LDS_BYTES 24576u    // + wid*6144 : q/P'/ctx'(2KB) | k(2KB) | v'(2KB)

// ---- workspace ----
#define WS_QKVW 0u          // 8 heads x 48 frags x 1KB  (frag = (ct*8+ks)*1024 + lane*16)
#define WS_OUTW 393216u     // 128 frags x 1KB           (frag = (ft*8+ks)*1024 + lane*16)
#define WS_QB   524288u     // [8][96] f32

// mask rows (bits 0..25); rows 26..31 dummy bit0 keeps pad rows finite
__constant__ u32 MASK32[32] = {
  0x0210000Fu,0x0210000Fu,0x0210000Fu,0x0210000Fu,
  0x026000F0u,0x026000F0u,0x026000F0u,0x026000F0u,
  0x03800F00u,0x03800F00u,0x03800F00u,0x03800F00u,
  0x0200F000u,0x0200F000u,0x0200F000u,0x0200F000u,
  0x020F0000u,0x020F0000u,0x020F0000u,0x020F0000u,
  0x0210000Fu,
  0x026000F0u,0x026000F0u,
  0x03800F00u,0x03800F00u,
  0x03FFFFFFu,
  0x1u,0x1u,0x1u,0x1u,0x1u,0x1u
};

__device__ __forceinline__ u16 f2bf(float f) {
  u32 u = __float_as_uint(f);
  u = (u + 0x7FFFu + ((u >> 16) & 1u)) >> 16;
  return (u16)u;
}
__device__ __forceinline__ u32 pk2(float a, float b) {
  return (u32)f2bf(a) | ((u32)f2bf(b) << 16);
}
__device__ __forceinline__ uint2 pk4(float a, float b, float c, float d) {
  uint2 r; r.x = pk2(a, b); r.y = pk2(c, d); return r;
}
// bijective 64B-row swizzle: XOR on the FULL byte offset (round-3-verified)
__device__ __forceinline__ u32 sw64(int row, int col2) {
  return (u32)((row * 64 + col2) ^ ((row & 7) << 4));
}

// ---- prep: fragment-order bf16 weight images + packed bias ----
__global__ __launch_bounds__(256)
void prep(const float* __restrict__ qkv_w, const float* __restrict__ qkv_b,
          const float* __restrict__ out_w, unsigned char* __restrict__ ws)
{
  int t = blockIdx.x * 256 + threadIdx.x;
  if (t < 24576) {                       // qkv frags: 8h x 48fr x 64 lanes
    int h = t / 3072, rem = t - h * 3072;
    int fr = rem >> 6, ln = rem & 63;
    int ct = fr >> 3, ks = fr & 7;
    int lr = ln & 15, lg = ln >> 4;
    int fg = (ct >> 1) * 256 + h * 32 + (ct & 1) * 16 + lr;
    const float* s = qkv_w + fg * 256 + ks * 32 + lg * 8;
    float4 v0 = *(const float4*)s, v1 = *(const float4*)(s + 4);
    uint4 o;
    o.x = pk2(v0.x, v0.y); o.y = pk2(v0.z, v0.w);
    o.z = pk2(v1.x, v1.y); o.w = pk2(v1.z, v1.w);
    *(uint4*)(ws + WS_QKVW + (u32)h * 49152u + (u32)fr * 1024u + (u32)ln * 16u) = o;
  } else if (t < 32768) {                // outw frags: 128fr x 64 lanes
    int g = t - 24576;
    int fr = g >> 6, ln = g & 63;
    int ft = fr >> 3, ks = fr & 7;
    int lr = ln & 15, lg = ln >> 4;
    const float* s = out_w + (ft * 16 + lr) * 256 + ks * 32 + lg * 8;
    float4 v0 = *(const float4*)s, v1 = *(const float4*)(s + 4);
    uint4 o;
    o.x = pk2(v0.x, v0.y); o.y = pk2(v0.z, v0.w);
    o.z = pk2(v1.x, v1.y); o.w = pk2(v1.z, v1.w);
    *(uint4*)(ws + WS_OUTW + (u32)fr * 1024u + (u32)ln * 16u) = o;
  } else if (t < 33536) {                // qkv bias [8][96]
    int i = t - 32768;
    int h = i / 96, j = i - h * 96;
    int ct = j >> 4, lr = j & 15;
    ((float*)(ws + WS_QB))[i] = qkv_b[(ct >> 1) * 256 + h * 32 + (ct & 1) * 16 + lr];
  }
}

// Pin the register tier: min=max=4 waves/EU -> VGPR cap 128, and no
// incentive for the allocator to shrink to the 64-reg tier (round-6 spill).
__global__ __attribute__((amdgpu_flat_work_group_size(256, 256), amdgpu_waves_per_eu(4, 4)))
void brain_fused(const float* __restrict__ x,
                 const unsigned char* __restrict__ ws,
                 const float* __restrict__ out_b,
                 float* __restrict__ out)
{
  __shared__ char smem[LDS_BYTES] __attribute__((aligned(16)));
  const int tid  = threadIdx.x;
  const int lane = tid & 63;
  const int wid  = tid >> 6;          // 0..3 = batch within block
  const int lr   = lane & 15;
  const int lg   = lane >> 4;
  const size_t rb = (size_t)blockIdx.x * 104 + (size_t)wid * 26;
  const f32x4 zero = {0.f, 0.f, 0.f, 0.f};
  const u32 sb = (u32)wid * 6144u;    // q/P'/ctx' @ sb, k @ +2048, v' @ +4096

  // ---- x A-fragments into registers (reused for all 8 heads) ----
  bf16x8 af[2][8];
#pragma unroll
  for (int st = 0; st < 2; ++st) {
    int s = st * 16 + lr;
    const float* xp = x + (rb + (size_t)(s < 26 ? s : 0)) * 256;
#pragma unroll
    for (int ks = 0; ks < 8; ++ks) {
      const float* p = xp + ks * 32 + lg * 8;
      float4 v0 = *(const float4*)p, v1 = *(const float4*)(p + 4);
      union { u32 u[4]; bf16x8 v; } tt;
      tt.u[0] = pk2(v0.x, v0.y); tt.u[1] = pk2(v0.z, v0.w);
      tt.u[2] = pk2(v1.x, v1.y); tt.u[3] = pk2(v1.z, v1.w);
      af[st][ks] = tt.v;
    }
  }

  const u32 mq0 = MASK32[lr];
  const u32 mq1 = MASK32[16 + lr];
  const float* qb = (const float*)(ws + WS_QB);

  bf16x8 cf[8][2];                     // ctx frags (A-operand of out-proj)

#pragma unroll
  for (int h = 0; h < 8; ++h) {
    const unsigned char* wh = ws + WS_QKVW + (u32)h * 49152u;

    // ---- QKV GEMM: 32 rows x 96 feats, K=256; bias in acc init ----
    f32x4 acc[2][6];
#pragma unroll
    for (int ct = 0; ct < 6; ++ct) {
      float bb = qb[h * 96 + ct * 16 + lr];
      f32x4 bv = {bb, bb, bb, bb};
      acc[0][ct] = bv; acc[1][ct] = bv;
    }
#pragma unroll
    for (int ks = 0; ks < 8; ++ks) {
      // two groups of 3 B-frags to cap live registers (round-6 spill fix)
#pragma unroll
      for (int g = 0; g < 2; ++g) {
        bf16x8 bw[3];
#pragma unroll
        for (int c = 0; c < 3; ++c)
          bw[c] = *(const bf16x8*)(wh + (u32)(((g * 3 + c) * 8 + ks) * 1024) + (u32)lane * 16u);
#pragma unroll
        for (int st = 0; st < 2; ++st)
#pragma unroll
          for (int c = 0; c < 3; ++c)
            acc[st][g * 3 + c] =
                __builtin_amdgcn_mfma_f32_16x16x32_bf16(af[st][ks], bw[c], acc[st][g * 3 + c], 0, 0, 0);
      }
    }

    // ---- scratch: q[s][d], k[s][d] scalar; v'[d][s] packed b64 ----
#pragma unroll
    for (int st = 0; st < 2; ++st)
#pragma unroll
      for (int ct = 0; ct < 4; ++ct)
#pragma unroll
        for (int r = 0; r < 4; ++r) {
          int s = st * 16 + lg * 4 + r;
          if (s < 26) {
            int d = (ct & 1) * 16 + lr;
            u32 a = sb + (ct < 2 ? 0u : 2048u) + sw64(s, d * 2);
            *(u16*)(smem + a) = f2bf(acc[st][ct][r]);
          }
        }
#pragma unroll
    for (int st = 0; st < 2; ++st)
#pragma unroll
      for (int ct = 4; ct < 6; ++ct) {
        int d = (ct & 1) * 16 + lr;
        u32 a = sb + 4096u + sw64(d, (st * 16 + lg * 4) * 2);
        *(uint2*)(smem + a) = pk4(acc[st][ct][0], acc[st][ct][1], acc[st][ct][2], acc[st][ct][3]);
      }

    // ---- frag reads ----
    bf16x8 qf[2], kf[2], vf[2];
#pragma unroll
    for (int t = 0; t < 2; ++t) {
      u32 ro = sw64(t * 16 + lr, lg * 16);
      qf[t] = *(const bf16x8*)(smem + sb + ro);
      kf[t] = *(const bf16x8*)(smem + sb + 2048u + ro);
      vf[t] = *(const bf16x8*)(smem + sb + 4096u + ro);
    }

    // ---- scores^T = K * Q^T ----
    f32x4 sc[2][2];  // [s_k half][q half]
#pragma unroll
    for (int st = 0; st < 2; ++st)
#pragma unroll
      for (int qt = 0; qt < 2; ++qt)
        sc[st][qt] = __builtin_amdgcn_mfma_f32_16x16x32_bf16(kf[st], qf[qt], zero, 0, 0, 0);

    // ---- masked softmax over s_k (per q column); P'[q][s] packed b64 ----
#pragma unroll
    for (int qt = 0; qt < 2; ++qt) {
      u32 mrow = qt ? mq1 : mq0;
      float mx = -3.0e38f;
#pragma unroll
      for (int st = 0; st < 2; ++st)
#pragma unroll
        for (int r = 0; r < 4; ++r) {
          int sk = st * 16 + lg * 4 + r;
          if ((mrow >> sk) & 1u) mx = fmaxf(mx, sc[st][qt][r]);
        }
      mx = fmaxf(mx, __shfl_xor(mx, 16));
      mx = fmaxf(mx, __shfl_xor(mx, 32));
      float pex[2][4];
      float sum = 0.f;
#pragma unroll
      for (int st = 0; st < 2; ++st)
#pragma unroll
        for (int r = 0; r < 4; ++r) {
          int sk = st * 16 + lg * 4 + r;
          // exp(s/sqrt(32)) = exp2(s * log2(e)/sqrt(32))
          float p = ((mrow >> sk) & 1u) ? exp2f((sc[st][qt][r] - mx) * 0.25505277f) : 0.f;
          pex[st][r] = p; sum += p;
        }
      sum += __shfl_xor(sum, 16);
      sum += __shfl_xor(sum, 32);
      float ri = __builtin_amdgcn_rcpf(sum);
      int q = qt * 16 + lr;
#pragma unroll
      for (int st = 0; st < 2; ++st) {
        u32 a = sb + sw64(q, (st * 16 + lg * 4) * 2);
        *(uint2*)(smem + a) = pk4(pex[st][0] * ri, pex[st][1] * ri, pex[st][2] * ri, pex[st][3] * ri);
      }
    }

    // ---- ctx^T = V^T * P^T ----
    bf16x8 pf[2];
#pragma unroll
    for (int qt = 0; qt < 2; ++qt)
      pf[qt] = *(const bf16x8*)(smem + sb + sw64(qt * 16 + lr, lg * 16));
    f32x4 pv[2][2];  // [d half][q half]
#pragma unroll
    for (int dt = 0; dt < 2; ++dt)
#pragma unroll
      for (int qt = 0; qt < 2; ++qt)
        pv[dt][qt] = __builtin_amdgcn_mfma_f32_16x16x32_bf16(vf[dt], pf[qt], zero, 0, 0, 0);

    // ctx'[q][d] packed b64, then read ctx frags
#pragma unroll
    for (int dt = 0; dt < 2; ++dt)
#pragma unroll
      for (int qt = 0; qt < 2; ++qt) {
        int q = qt * 16 + lr;
        u32 a = sb + sw64(q, (dt * 16 + lg * 4) * 2);
        *(uint2*)(smem + a) = pk4(pv[dt][qt][0], pv[dt][qt][1], pv[dt][qt][2], pv[dt][qt][3]);
      }
#pragma unroll
    for (int qt = 0; qt < 2; ++qt)
      cf[h][qt] = *(const bf16x8*)(smem + sb + sw64(qt * 16 + lr, lg * 16));
  } // heads

  // ---- out-projection: out[q][f] = sum_h ctx_h @ outw_h^T + out_b ----
#pragma unroll
  for (int fc = 0; fc < 4; ++fc) {
    f32x4 oa[2][4];
#pragma unroll
    for (int j = 0; j < 4; ++j) {
      float bo = out_b[(fc * 4 + j) * 16 + lr];
      f32x4 bv = {bo, bo, bo, bo};
      oa[0][j] = bv; oa[1][j] = bv;
    }
#pragma unroll
    for (int ks = 0; ks < 8; ++ks) {
      bf16x8 bw[4];
#pragma unroll
      for (int j = 0; j < 4; ++j)
        bw[j] = *(const bf16x8*)(ws + WS_OUTW + (u32)(((fc * 4 + j) * 8 + ks) * 1024) + (u32)lane * 16u);
#pragma unroll
      for (int qt = 0; qt < 2; ++qt)
#pragma unroll
        for (int j = 0; j < 4; ++j)
          oa[qt][j] = __builtin_amdgcn_mfma_f32_16x16x32_bf16(cf[ks][qt], bw[j], oa[qt][j], 0, 0, 0);
    }
#pragma unroll
    for (int qt = 0; qt < 2; ++qt)
#pragma unroll
      for (int j = 0; j < 4; ++j)
#pragma unroll
        for (int r = 0; r < 4; ++r) {
          int qrow = qt * 16 + lg * 4 + r;
          if (qrow < 26)
            out[(rb + (size_t)qrow) * 256 + (fc * 4 + j) * 16 + lr] = oa[qt][j][r];
        }
  }
}

extern "C" void kernel_launch(void* const* d_in, const int* in_sizes, int n_in,
                              void* d_out, int out_size, void* d_ws, size_t ws_size,
                              hipStream_t stream) {
  (void)in_sizes; (void)n_in; (void)out_size; (void)ws_size;
  const float* x     = (const float*)d_in[0];
  const float* qkv_w = (const float*)d_in[1];
  const float* qkv_b = (const float*)d_in[2];
  const float* out_w = (const float*)d_in[3];
  const float* out_b = (const float*)d_in[4];
  unsigned char* ws = (unsigned char*)d_ws;
  float* out = (float*)d_out;

  prep<<<dim3(131), dim3(256), 0, stream>>>(qkv_w, qkv_b, out_w, ws);
  brain_fused<<<dim3(4096), dim3(256), 0, stream>>>(x, ws, out_b, out);
}

// Round 8
// 600.827 us; speedup vs baseline: 2.1020x; 1.8768x over previous
//
#include <hip/hip_runtime.h>
#include <hip/hip_bf16.h>

typedef short bf16x8 __attribute__((ext_vector_type(8)));
typedef float f32x4  __attribute__((ext_vector_type(4)));
typedef unsigned short u16;
typedef unsigned int u32;

// ---- LDS: 4 waves x 6KB private transpose scratch, nothing else ----
#define LDS_BYTES 24576u    // + wid*6144 : q/P'/ctx'(2KB) | k(2KB) | v'(2KB)

// ---- workspace ----
#define WS_QKVW 0u          // 8 heads x 48 frags x 1KB  (frag = (ct*8+ks)*1024 + lane*16)
#define WS_OUTW 393216u     // 128 frags x 1KB           (frag = (ft*8+ks)*1024 + lane*16)
#define WS_QB   524288u     // [8][96] f32

// mask rows (bits 0..25); rows 26..31 dummy bit0 keeps pad rows finite
__constant__ u32 MASK32[32] = {
  0x0210000Fu,0x0210000Fu,0x0210000Fu,0x0210000Fu,
  0x026000F0u,0x026000F0u,0x026000F0u,0x026000F0u,
  0x03800F00u,0x03800F00u,0x03800F00u,0x03800F00u,
  0x0200F000u,0x0200F000u,0x0200F000u,0x0200F000u,
  0x020F0000u,0x020F0000u,0x020F0000u,0x020F0000u,
  0x0210000Fu,
  0x026000F0u,0x026000F0u,
  0x03800F00u,0x03800F00u,
  0x03FFFFFFu,
  0x1u,0x1u,0x1u,0x1u,0x1u,0x1u
};

__device__ __forceinline__ u16 f2bf(float f) {
  u32 u = __float_as_uint(f);
  u = (u + 0x7FFFu + ((u >> 16) & 1u)) >> 16;
  return (u16)u;
}
__device__ __forceinline__ u32 pk2(float a, float b) {
  return (u32)f2bf(a) | ((u32)f2bf(b) << 16);
}
__device__ __forceinline__ uint2 pk4(float a, float b, float c, float d) {
  uint2 r; r.x = pk2(a, b); r.y = pk2(c, d); return r;
}
// bijective 64B-row swizzle: XOR on the FULL byte offset (round-3-verified)
__device__ __forceinline__ u32 sw64(int row, int col2) {
  return (u32)((row * 64 + col2) ^ ((row & 7) << 4));
}

// ---- prep: fragment-order bf16 weight images + packed bias ----
__global__ __launch_bounds__(256)
void prep(const float* __restrict__ qkv_w, const float* __restrict__ qkv_b,
          const float* __restrict__ out_w, unsigned char* __restrict__ ws)
{
  int t = blockIdx.x * 256 + threadIdx.x;
  if (t < 24576) {                       // qkv frags: 8h x 48fr x 64 lanes
    int h = t / 3072, rem = t - h * 3072;
    int fr = rem >> 6, ln = rem & 63;
    int ct = fr >> 3, ks = fr & 7;
    int lr = ln & 15, lg = ln >> 4;
    int fg = (ct >> 1) * 256 + h * 32 + (ct & 1) * 16 + lr;
    const float* s = qkv_w + fg * 256 + ks * 32 + lg * 8;
    float4 v0 = *(const float4*)s, v1 = *(const float4*)(s + 4);
    uint4 o;
    o.x = pk2(v0.x, v0.y); o.y = pk2(v0.z, v0.w);
    o.z = pk2(v1.x, v1.y); o.w = pk2(v1.z, v1.w);
    *(uint4*)(ws + WS_QKVW + (u32)h * 49152u + (u32)fr * 1024u + (u32)ln * 16u) = o;
  } else if (t < 32768) {                // outw frags: 128fr x 64 lanes
    int g = t - 24576;
    int fr = g >> 6, ln = g & 63;
    int ft = fr >> 3, ks = fr & 7;
    int lr = ln & 15, lg = ln >> 4;
    const float* s = out_w + (ft * 16 + lr) * 256 + ks * 32 + lg * 8;
    float4 v0 = *(const float4*)s, v1 = *(const float4*)(s + 4);
    uint4 o;
    o.x = pk2(v0.x, v0.y); o.y = pk2(v0.z, v0.w);
    o.z = pk2(v1.x, v1.y); o.w = pk2(v1.z, v1.w);
    *(uint4*)(ws + WS_OUTW + (u32)fr * 1024u + (u32)ln * 16u) = o;
  } else if (t < 33536) {                // qkv bias [8][96]
    int i = t - 32768;
    int h = i / 96, j = i - h * 96;
    int ct = j >> 4, lr = j & 15;
    ((float*)(ws + WS_QB))[i] = qkv_b[(ct >> 1) * 256 + h * 32 + (ct & 1) * 16 + lr];
  }
}

// 256-reg tier (128 arch VGPR + AGPR): the ~190-reg live state fits; round-5
// proved this tier runs spill-free. 2 blocks/CU.
__global__ __launch_bounds__(256, 2)
void brain_fused(const float* __restrict__ x,
                 const unsigned char* __restrict__ ws,
                 const float* __restrict__ out_b,
                 float* __restrict__ out)
{
  __shared__ char smem[LDS_BYTES] __attribute__((aligned(16)));
  const int tid  = threadIdx.x;
  const int lane = tid & 63;
  const int wid  = tid >> 6;          // 0..3 = batch within block
  const int lr   = lane & 15;
  const int lg   = lane >> 4;
  const size_t rb = (size_t)blockIdx.x * 104 + (size_t)wid * 26;
  const f32x4 zero = {0.f, 0.f, 0.f, 0.f};
  const u32 sb = (u32)wid * 6144u;    // q/P'/ctx' @ sb, k @ +2048, v' @ +4096

  // ---- x A-fragments into registers (reused for all 8 heads) ----
  // pad rows s>=26: zeros (no load). P' masking keeps downstream exact.
  bf16x8 af[2][8];
#pragma unroll
  for (int st = 0; st < 2; ++st) {
    int s = st * 16 + lr;
    const float* xp = x + (rb + (size_t)s) * 256;
#pragma unroll
    for (int ks = 0; ks < 8; ++ks) {
      if (s < 26) {
        const float* p = xp + ks * 32 + lg * 8;
        float4 v0 = *(const float4*)p, v1 = *(const float4*)(p + 4);
        union { u32 u[4]; bf16x8 v; } tt;
        tt.u[0] = pk2(v0.x, v0.y); tt.u[1] = pk2(v0.z, v0.w);
        tt.u[2] = pk2(v1.x, v1.y); tt.u[3] = pk2(v1.z, v1.w);
        af[st][ks] = tt.v;
      } else {
        af[st][ks] = (bf16x8)(short)0;
      }
    }
  }

  const u32 mq0 = MASK32[lr];
  const u32 mq1 = MASK32[16 + lr];
  const float* qb = (const float*)(ws + WS_QB);

  bf16x8 cf[8][2];                     // ctx frags (A-operand of out-proj)

#pragma unroll
  for (int h = 0; h < 8; ++h) {
    const unsigned char* wh = ws + WS_QKVW + (u32)h * 49152u;

    // ---- QKV GEMM: 32 rows x 96 feats, K=256; bias in acc init ----
    f32x4 acc[2][6];
#pragma unroll
    for (int ct = 0; ct < 6; ++ct) {
      float bb = qb[h * 96 + ct * 16 + lr];
      f32x4 bv = {bb, bb, bb, bb};
      acc[0][ct] = bv; acc[1][ct] = bv;
    }
#pragma unroll
    for (int ks = 0; ks < 8; ++ks) {
      bf16x8 bw[6];
#pragma unroll
      for (int ct = 0; ct < 6; ++ct)
        bw[ct] = *(const bf16x8*)(wh + (u32)((ct * 8 + ks) * 1024) + (u32)lane * 16u);
#pragma unroll
      for (int st = 0; st < 2; ++st)
#pragma unroll
        for (int ct = 0; ct < 6; ++ct)
          acc[st][ct] = __builtin_amdgcn_mfma_f32_16x16x32_bf16(af[st][ks], bw[ct], acc[st][ct], 0, 0, 0);
    }

    // ---- scratch: q[s][d], k[s][d] scalar; v'[d][s] packed b64 ----
#pragma unroll
    for (int st = 0; st < 2; ++st)
#pragma unroll
      for (int ct = 0; ct < 4; ++ct)
#pragma unroll
        for (int r = 0; r < 4; ++r) {
          int s = st * 16 + lg * 4 + r;
          if (s < 26) {
            int d = (ct & 1) * 16 + lr;
            u32 a = sb + (ct < 2 ? 0u : 2048u) + sw64(s, d * 2);
            *(u16*)(smem + a) = f2bf(acc[st][ct][r]);
          }
        }
#pragma unroll
    for (int st = 0; st < 2; ++st)
#pragma unroll
      for (int ct = 4; ct < 6; ++ct) {
        int d = (ct & 1) * 16 + lr;
        u32 a = sb + 4096u + sw64(d, (st * 16 + lg * 4) * 2);
        *(uint2*)(smem + a) = pk4(acc[st][ct][0], acc[st][ct][1], acc[st][ct][2], acc[st][ct][3]);
      }

    // ---- frag reads ----
    bf16x8 qf[2], kf[2], vf[2];
#pragma unroll
    for (int t = 0; t < 2; ++t) {
      u32 ro = sw64(t * 16 + lr, lg * 16);
      qf[t] = *(const bf16x8*)(smem + sb + ro);
      kf[t] = *(const bf16x8*)(smem + sb + 2048u + ro);
      vf[t] = *(const bf16x8*)(smem + sb + 4096u + ro);
    }

    // ---- scores^T = K * Q^T ----
    f32x4 sc[2][2];  // [s_k half][q half]
#pragma unroll
    for (int st = 0; st < 2; ++st)
#pragma unroll
      for (int qt = 0; qt < 2; ++qt)
        sc[st][qt] = __builtin_amdgcn_mfma_f32_16x16x32_bf16(kf[st], qf[qt], zero, 0, 0, 0);

    // ---- masked softmax over s_k (per q column); P'[q][s] packed b64 ----
#pragma unroll
    for (int qt = 0; qt < 2; ++qt) {
      u32 mrow = qt ? mq1 : mq0;
      float mx = -3.0e38f;
#pragma unroll
      for (int st = 0; st < 2; ++st)
#pragma unroll
        for (int r = 0; r < 4; ++r) {
          int sk = st * 16 + lg * 4 + r;
          if ((mrow >> sk) & 1u) mx = fmaxf(mx, sc[st][qt][r]);
        }
      mx = fmaxf(mx, __shfl_xor(mx, 16));
      mx = fmaxf(mx, __shfl_xor(mx, 32));
      float pex[2][4];
      float sum = 0.f;
#pragma unroll
      for (int st = 0; st < 2; ++st)
#pragma unroll
        for (int r = 0; r < 4; ++r) {
          int sk = st * 16 + lg * 4 + r;
          // exp(s/sqrt(32)) = exp2(s * log2(e)/sqrt(32))
          float p = ((mrow >> sk) & 1u) ? exp2f((sc[st][qt][r] - mx) * 0.25505277f) : 0.f;
          pex[st][r] = p; sum += p;
        }
      sum += __shfl_xor(sum, 16);
      sum += __shfl_xor(sum, 32);
      float ri = __builtin_amdgcn_rcpf(sum);
      int q = qt * 16 + lr;
#pragma unroll
      for (int st = 0; st < 2; ++st) {
        u32 a = sb + sw64(q, (st * 16 + lg * 4) * 2);
        *(uint2*)(smem + a) = pk4(pex[st][0] * ri, pex[st][1] * ri, pex[st][2] * ri, pex[st][3] * ri);
      }
    }

    // ---- ctx^T = V^T * P^T ----
    bf16x8 pf[2];
#pragma unroll
    for (int qt = 0; qt < 2; ++qt)
      pf[qt] = *(const bf16x8*)(smem + sb + sw64(qt * 16 + lr, lg * 16));
    f32x4 pv[2][2];  // [d half][q half]
#pragma unroll
    for (int dt = 0; dt < 2; ++dt)
#pragma unroll
      for (int qt = 0; qt < 2; ++qt)
        pv[dt][qt] = __builtin_amdgcn_mfma_f32_16x16x32_bf16(vf[dt], pf[qt], zero, 0, 0, 0);

    // ctx'[q][d] packed b64, then read ctx frags
#pragma unroll
    for (int dt = 0; dt < 2; ++dt)
#pragma unroll
      for (int qt = 0; qt < 2; ++qt) {
        int q = qt * 16 + lr;
        u32 a = sb + sw64(q, (dt * 16 + lg * 4) * 2);
        *(uint2*)(smem + a) = pk4(pv[dt][qt][0], pv[dt][qt][1], pv[dt][qt][2], pv[dt][qt][3]);
      }
#pragma unroll
    for (int qt = 0; qt < 2; ++qt)
      cf[h][qt] = *(const bf16x8*)(smem + sb + sw64(qt * 16 + lr, lg * 16));
  } // heads

  // ---- out-projection: out[q][f] = sum_h ctx_h @ outw_h^T + out_b ----
#pragma unroll
  for (int fc = 0; fc < 4; ++fc) {
    f32x4 oa[2][4];
#pragma unroll
    for (int j = 0; j < 4; ++j) {
      float bo = out_b[(fc * 4 + j) * 16 + lr];
      f32x4 bv = {bo, bo, bo, bo};
      oa[0][j] = bv; oa[1][j] = bv;
    }
#pragma unroll
    for (int ks = 0; ks < 8; ++ks) {
      bf16x8 bw[4];
#pragma unroll
      for (int j = 0; j < 4; ++j)
        bw[j] = *(const bf16x8*)(ws + WS_OUTW + (u32)(((fc * 4 + j) * 8 + ks) * 1024) + (u32)lane * 16u);
#pragma unroll
      for (int qt = 0; qt < 2; ++qt)
#pragma unroll
        for (int j = 0; j < 4; ++j)
          oa[qt][j] = __builtin_amdgcn_mfma_f32_16x16x32_bf16(cf[ks][qt], bw[j], oa[qt][j], 0, 0, 0);
    }
#pragma unroll
    for (int qt = 0; qt < 2; ++qt)
#pragma unroll
      for (int j = 0; j < 4; ++j)
#pragma unroll
        for (int r = 0; r < 4; ++r) {
          int qrow = qt * 16 + lg * 4 + r;
          if (qrow < 26)
            out[(rb + (size_t)qrow) * 256 + (fc * 4 + j) * 16 + lr] = oa[qt][j][r];
        }
  }
}

extern "C" void kernel_launch(void* const* d_in, const int* in_sizes, int n_in,
                              void* d_out, int out_size, void* d_ws, size_t ws_size,
                              hipStream_t stream) {
  (void)in_sizes; (void)n_in; (void)out_size; (void)ws_size;
  const float* x     = (const float*)d_in[0];
  const float* qkv_w = (const float*)d_in[1];
  const float* qkv_b = (const float*)d_in[2];
  const float* out_w = (const float*)d_in[3];
  const float* out_b = (const float*)d_in[4];
  unsigned char* ws = (unsigned char*)d_ws;
  float* out = (float*)d_out;

  prep<<<dim3(131), dim3(256), 0, stream>>>(qkv_w, qkv_b, out_w, ws);
  brain_fused<<<dim3(4096), dim3(256), 0, stream>>>(x, ws, out_b, out);
}

// Round 9
// 502.392 us; speedup vs baseline: 2.5138x; 1.1959x over previous
//
#include <hip/hip_runtime.h>
#include <hip/hip_bf16.h>

typedef short bf16x8 __attribute__((ext_vector_type(8)));
typedef float f32x4  __attribute__((ext_vector_type(4)));
typedef unsigned short u16;
typedef unsigned int u32;

// ---- LDS: W frag-image 48KB + 4 waves x 6KB private scratch = 72KB (2 blocks/CU) ----
#define LDS_W     0u
#define LDS_SCR   49152u
#define LDS_BYTES 73728u

// ---- workspace ----
#define WS_QKVW 0u          // 8 heads x 48 frags x 1KB  (frag = (ct*8+ks)*1024 + lane*16)
#define WS_OUTW 393216u     // 4 chunks x 32KB (chunk fc: frags (j*8+ks), j=0..3 local)
#define WS_QB   524288u     // [8][96] f32

// mask rows (bits 0..25); rows 26..31 dummy bit0 keeps pad rows finite
__constant__ u32 MASK32[32] = {
  0x0210000Fu,0x0210000Fu,0x0210000Fu,0x0210000Fu,
  0x026000F0u,0x026000F0u,0x026000F0u,0x026000F0u,
  0x03800F00u,0x03800F00u,0x03800F00u,0x03800F00u,
  0x0200F000u,0x0200F000u,0x0200F000u,0x0200F000u,
  0x020F0000u,0x020F0000u,0x020F0000u,0x020F0000u,
  0x0210000Fu,
  0x026000F0u,0x026000F0u,
  0x03800F00u,0x03800F00u,
  0x03FFFFFFu,
  0x1u,0x1u,0x1u,0x1u,0x1u,0x1u
};

__device__ __forceinline__ u16 f2bf(float f) {
  u32 u = __float_as_uint(f);
  u = (u + 0x7FFFu + ((u >> 16) & 1u)) >> 16;
  return (u16)u;
}
__device__ __forceinline__ u32 pk2(float a, float b) {
  return (u32)f2bf(a) | ((u32)f2bf(b) << 16);
}
__device__ __forceinline__ uint2 pk4(float a, float b, float c, float d) {
  uint2 r; r.x = pk2(a, b); r.y = pk2(c, d); return r;
}
// bijective 64B-row swizzle: XOR on the FULL byte offset (round-3-verified)
__device__ __forceinline__ u32 sw64(int row, int col2) {
  return (u32)((row * 64 + col2) ^ ((row & 7) << 4));
}

// ---- prep: fragment-order bf16 weight images + packed bias ----
__global__ __launch_bounds__(256)
void prep(const float* __restrict__ qkv_w, const float* __restrict__ qkv_b,
          const float* __restrict__ out_w, unsigned char* __restrict__ ws)
{
  int t = blockIdx.x * 256 + threadIdx.x;
  if (t < 24576) {                       // qkv frags: 8h x 48fr x 64 lanes
    int h = t / 3072, rem = t - h * 3072;
    int fr = rem >> 6, ln = rem & 63;
    int ct = fr >> 3, ks = fr & 7;
    int lr = ln & 15, lg = ln >> 4;
    int fg = (ct >> 1) * 256 + h * 32 + (ct & 1) * 16 + lr;
    const float* s = qkv_w + fg * 256 + ks * 32 + lg * 8;
    float4 v0 = *(const float4*)s, v1 = *(const float4*)(s + 4);
    uint4 o;
    o.x = pk2(v0.x, v0.y); o.y = pk2(v0.z, v0.w);
    o.z = pk2(v1.x, v1.y); o.w = pk2(v1.z, v1.w);
    *(uint4*)(ws + WS_QKVW + (u32)h * 49152u + (u32)fr * 1024u + (u32)ln * 16u) = o;
  } else if (t < 32768) {                // outw frags: 128fr x 64 lanes
    int g = t - 24576;
    int fr = g >> 6, ln = g & 63;
    int ft = fr >> 3, ks = fr & 7;
    int lr = ln & 15, lg = ln >> 4;
    const float* s = out_w + (ft * 16 + lr) * 256 + ks * 32 + lg * 8;
    float4 v0 = *(const float4*)s, v1 = *(const float4*)(s + 4);
    uint4 o;
    o.x = pk2(v0.x, v0.y); o.y = pk2(v0.z, v0.w);
    o.z = pk2(v1.x, v1.y); o.w = pk2(v1.z, v1.w);
    *(uint4*)(ws + WS_OUTW + (u32)fr * 1024u + (u32)ln * 16u) = o;
  } else if (t < 33536) {                // qkv bias [8][96]
    int i = t - 32768;
    int h = i / 96, j = i - h * 96;
    int ct = j >> 4, lr = j & 15;
    ((float*)(ws + WS_QB))[i] = qkv_b[(ct >> 1) * 256 + h * 32 + (ct & 1) * 16 + lr];
  }
}

// 256-reg tier (2 blocks/CU): ~200-reg live state fits spill-free (round-5/8 verified tier).
__global__ __launch_bounds__(256, 2)
void brain_fused(const float* __restrict__ x,
                 const unsigned char* __restrict__ ws,
                 const float* __restrict__ out_b,
                 float* __restrict__ out)
{
  __shared__ char smem[LDS_BYTES] __attribute__((aligned(16)));
  const int tid  = threadIdx.x;
  const int lane = tid & 63;
  const int wid  = tid >> 6;          // 0..3 = batch within block
  const int lr   = lane & 15;
  const int lg   = lane >> 4;
  const size_t rb = (size_t)blockIdx.x * 104 + (size_t)wid * 26;
  const f32x4 zero = {0.f, 0.f, 0.f, 0.f};
  const u32 sb = LDS_SCR + (u32)wid * 6144u;  // q/P'/ctx' @ sb, k @ +2048, v' @ +4096

  // ---- x A-fragments into registers (reused for all 8 heads); pad rows = 0 ----
  bf16x8 af[2][8];
#pragma unroll
  for (int st = 0; st < 2; ++st) {
    int s = st * 16 + lr;
    const float* xp = x + (rb + (size_t)s) * 256;
#pragma unroll
    for (int ks = 0; ks < 8; ++ks) {
      if (s < 26) {
        const float* p = xp + ks * 32 + lg * 8;
        float4 v0 = *(const float4*)p, v1 = *(const float4*)(p + 4);
        union { u32 u[4]; bf16x8 v; } tt;
        tt.u[0] = pk2(v0.x, v0.y); tt.u[1] = pk2(v0.z, v0.w);
        tt.u[2] = pk2(v1.x, v1.y); tt.u[3] = pk2(v1.z, v1.w);
        af[st][ks] = tt.v;
      } else {
        af[st][ks] = (bf16x8)(short)0;
      }
    }
  }

  const u32 mq0 = MASK32[lr];
  const u32 mq1 = MASK32[16 + lr];
  const float* qb = (const float*)(ws + WS_QB);

  // ---- pre-stage W(0) into LDS (pure 16B memcpy of frag image) ----
#pragma unroll
  for (int i = 0; i < 12; ++i) {
    int idx = tid + i * 256;
    *(uint4*)(smem + LDS_W + (u32)idx * 16u) = *(const uint4*)(ws + WS_QKVW + (u32)idx * 16u);
  }
  __syncthreads();

  bf16x8 cf[8][2];                     // ctx frags (A-operand of out-proj)

#pragma unroll
  for (int h = 0; h < 8; ++h) {
    // ---- QKV GEMM: 32 rows x 96 feats, K=256; B-frags from LDS; bias in acc ----
    f32x4 acc[2][6];
#pragma unroll
    for (int ct = 0; ct < 6; ++ct) {
      float bb = qb[h * 96 + ct * 16 + lr];
      f32x4 bv = {bb, bb, bb, bb};
      acc[0][ct] = bv; acc[1][ct] = bv;
    }
#pragma unroll
    for (int ks = 0; ks < 8; ++ks) {
      bf16x8 bw[6];
#pragma unroll
      for (int ct = 0; ct < 6; ++ct)
        bw[ct] = *(const bf16x8*)(smem + LDS_W + (u32)((ct * 8 + ks) << 10) + (u32)lane * 16u);
#pragma unroll
      for (int st = 0; st < 2; ++st)
#pragma unroll
        for (int ct = 0; ct < 6; ++ct)
          acc[st][ct] = __builtin_amdgcn_mfma_f32_16x16x32_bf16(af[st][ks], bw[ct], acc[st][ct], 0, 0, 0);
    }
    __syncthreads();  // b1: all waves done reading W(h)

    // T14 stage-split A: issue first 6 granules of next image (or out-proj chunk0)
    const unsigned char* nsrc = (h < 7) ? (ws + WS_QKVW + (u32)(h + 1) * 49152u)
                                        : (ws + WS_OUTW);
    const int nB = (h < 7) ? 6 : 2;    // total granules: 12 (48KB) or 8 (32KB)
    uint4 stA[6];
#pragma unroll
    for (int i = 0; i < 6; ++i)
      stA[i] = *(const uint4*)(nsrc + (u32)(tid + i * 256) * 16u);

    // ---- attention part 1: transposes, QK^T, softmax ----
#pragma unroll
    for (int st = 0; st < 2; ++st)
#pragma unroll
      for (int ct = 0; ct < 4; ++ct)
#pragma unroll
        for (int r = 0; r < 4; ++r) {
          int s = st * 16 + lg * 4 + r;
          if (s < 26) {
            int d = (ct & 1) * 16 + lr;
            u32 a = sb + (ct < 2 ? 0u : 2048u) + sw64(s, d * 2);
            *(u16*)(smem + a) = f2bf(acc[st][ct][r]);
          }
        }
#pragma unroll
    for (int st = 0; st < 2; ++st)
#pragma unroll
      for (int ct = 4; ct < 6; ++ct) {
        int d = (ct & 1) * 16 + lr;
        u32 a = sb + 4096u + sw64(d, (st * 16 + lg * 4) * 2);
        *(uint2*)(smem + a) = pk4(acc[st][ct][0], acc[st][ct][1], acc[st][ct][2], acc[st][ct][3]);
      }

    bf16x8 qf[2], kf[2], vf[2];
#pragma unroll
    for (int t = 0; t < 2; ++t) {
      u32 ro = sw64(t * 16 + lr, lg * 16);
      qf[t] = *(const bf16x8*)(smem + sb + ro);
      kf[t] = *(const bf16x8*)(smem + sb + 2048u + ro);
      vf[t] = *(const bf16x8*)(smem + sb + 4096u + ro);
    }

    f32x4 sc[2][2];  // [s_k half][q half]
#pragma unroll
    for (int st = 0; st < 2; ++st)
#pragma unroll
      for (int qt = 0; qt < 2; ++qt)
        sc[st][qt] = __builtin_amdgcn_mfma_f32_16x16x32_bf16(kf[st], qf[qt], zero, 0, 0, 0);

#pragma unroll
    for (int qt = 0; qt < 2; ++qt) {
      u32 mrow = qt ? mq1 : mq0;
      float mx = -3.0e38f;
#pragma unroll
      for (int st = 0; st < 2; ++st)
#pragma unroll
        for (int r = 0; r < 4; ++r) {
          int sk = st * 16 + lg * 4 + r;
          if ((mrow >> sk) & 1u) mx = fmaxf(mx, sc[st][qt][r]);
        }
      mx = fmaxf(mx, __shfl_xor(mx, 16));
      mx = fmaxf(mx, __shfl_xor(mx, 32));
      float pex[2][4];
      float sum = 0.f;
#pragma unroll
      for (int st = 0; st < 2; ++st)
#pragma unroll
        for (int r = 0; r < 4; ++r) {
          int sk = st * 16 + lg * 4 + r;
          // exp(s/sqrt(32)) = exp2(s * log2(e)/sqrt(32))
          float p = ((mrow >> sk) & 1u) ? exp2f((sc[st][qt][r] - mx) * 0.25505277f) : 0.f;
          pex[st][r] = p; sum += p;
        }
      sum += __shfl_xor(sum, 16);
      sum += __shfl_xor(sum, 32);
      float ri = __builtin_amdgcn_rcpf(sum);
      int q = qt * 16 + lr;
#pragma unroll
      for (int st = 0; st < 2; ++st) {
        u32 a = sb + sw64(q, (st * 16 + lg * 4) * 2);
        *(uint2*)(smem + a) = pk4(pex[st][0] * ri, pex[st][1] * ri, pex[st][2] * ri, pex[st][3] * ri);
      }
    }

    // stage-split: write A to LDS, issue B
#pragma unroll
    for (int i = 0; i < 6; ++i)
      *(uint4*)(smem + LDS_W + (u32)(tid + i * 256) * 16u) = stA[i];
    uint4 stB[6];
#pragma unroll
    for (int i = 0; i < 6; ++i)
      if (i < nB) stB[i] = *(const uint4*)(nsrc + (u32)(tid + (6 + i) * 256) * 16u);

    // ---- attention part 2: PV + ctx frags ----
    bf16x8 pf[2];
#pragma unroll
    for (int qt = 0; qt < 2; ++qt)
      pf[qt] = *(const bf16x8*)(smem + sb + sw64(qt * 16 + lr, lg * 16));
    f32x4 pv[2][2];  // [d half][q half]
#pragma unroll
    for (int dt = 0; dt < 2; ++dt)
#pragma unroll
      for (int qt = 0; qt < 2; ++qt)
        pv[dt][qt] = __builtin_amdgcn_mfma_f32_16x16x32_bf16(vf[dt], pf[qt], zero, 0, 0, 0);

#pragma unroll
    for (int dt = 0; dt < 2; ++dt)
#pragma unroll
      for (int qt = 0; qt < 2; ++qt) {
        int q = qt * 16 + lr;
        u32 a = sb + sw64(q, (dt * 16 + lg * 4) * 2);
        *(uint2*)(smem + a) = pk4(pv[dt][qt][0], pv[dt][qt][1], pv[dt][qt][2], pv[dt][qt][3]);
      }
#pragma unroll
    for (int qt = 0; qt < 2; ++qt)
      cf[h][qt] = *(const bf16x8*)(smem + sb + sw64(qt * 16 + lr, lg * 16));

    // stage-split: write B
#pragma unroll
    for (int i = 0; i < 6; ++i)
      if (i < nB) *(uint4*)(smem + LDS_W + (u32)(tid + (6 + i) * 256) * 16u) = stB[i];
    __syncthreads();  // b2: next LDS image (W(h+1) or out-proj chunk0) ready
  } // heads

  // ---- out-projection: 4 chunks of 64 cols; B-frags from LDS, prefetch next ----
#pragma unroll
  for (int fc = 0; fc < 4; ++fc) {
    f32x4 oa[2][4];
#pragma unroll
    for (int j = 0; j < 4; ++j) {
      float bo = out_b[(fc * 4 + j) * 16 + lr];
      f32x4 bv = {bo, bo, bo, bo};
      oa[0][j] = bv; oa[1][j] = bv;
    }
    uint4 pre[8];
    if (fc < 3)
#pragma unroll
      for (int i = 0; i < 8; ++i)
        pre[i] = *(const uint4*)(ws + WS_OUTW + (u32)(fc + 1) * 32768u + (u32)(tid + i * 256) * 16u);

#pragma unroll
    for (int ks = 0; ks < 8; ++ks) {
      bf16x8 bw[4];
#pragma unroll
      for (int j = 0; j < 4; ++j)
        bw[j] = *(const bf16x8*)(smem + LDS_W + (u32)((j * 8 + ks) << 10) + (u32)lane * 16u);
#pragma unroll
      for (int qt = 0; qt < 2; ++qt)
#pragma unroll
        for (int j = 0; j < 4; ++j)
          oa[qt][j] = __builtin_amdgcn_mfma_f32_16x16x32_bf16(cf[ks][qt], bw[j], oa[qt][j], 0, 0, 0);
    }
#pragma unroll
    for (int qt = 0; qt < 2; ++qt)
#pragma unroll
      for (int j = 0; j < 4; ++j)
#pragma unroll
        for (int r = 0; r < 4; ++r) {
          int qrow = qt * 16 + lg * 4 + r;
          if (qrow < 26)
            out[(rb + (size_t)qrow) * 256 + (fc * 4 + j) * 16 + lr] = oa[qt][j][r];
        }
    __syncthreads();  // all waves done reading chunk fc
    if (fc < 3) {
#pragma unroll
      for (int i = 0; i < 8; ++i)
        *(uint4*)(smem + LDS_W + (u32)(tid + i * 256) * 16u) = pre[i];
      __syncthreads();  // chunk fc+1 ready
    }
  }
}

extern "C" void kernel_launch(void* const* d_in, const int* in_sizes, int n_in,
                              void* d_out, int out_size, void* d_ws, size_t ws_size,
                              hipStream_t stream) {
  (void)in_sizes; (void)n_in; (void)out_size; (void)ws_size;
  const float* x     = (const float*)d_in[0];
  const float* qkv_w = (const float*)d_in[1];
  const float* qkv_b = (const float*)d_in[2];
  const float* out_w = (const float*)d_in[3];
  const float* out_b = (const float*)d_in[4];
  unsigned char* ws = (unsigned char*)d_ws;
  float* out = (float*)d_out;

  prep<<<dim3(131), dim3(256), 0, stream>>>(qkv_w, qkv_b, out_w, ws);
  brain_fused<<<dim3(4096), dim3(256), 0, stream>>>(x, ws, out_b, out);
}